// Round 9
// baseline (589.920 us; speedup 1.0000x reference)
//
#include <hip/hip_runtime.h>
#include <math.h>

typedef __bf16 bf16;
typedef __bf16 bf16x8 __attribute__((ext_vector_type(8)));
typedef float f32x4 __attribute__((ext_vector_type(4)));

#define HEADS 16
#define QHEAD 192
#define NB 2
#define SEQ 2048
#define ROWS (NB * SEQ)
/* q pre-scale = log2(e)/sqrt(192): scores arrive in exp2 domain */
#define QSCALE2 0.10411754584f
/* fixed softmax shift: p = 2^(sacc - CSHIFT) = exp(s_nat - 8) */
#define CSHIFT 11.5415603272f

// ---------------------------------------------------------------------------
// prep: x convert (0..8191) + weight transposes (8192..18047) +
// RoPE sin/cos table (18048..18303): tab[n*32+i] = {cos,sin}(n*10000^(-i/32))
// ---------------------------------------------------------------------------
__global__ __launch_bounds__(256) void prep(
    const float* __restrict__ x,
    const float* __restrict__ Wqa, const float* __restrict__ Wqb,
    const float* __restrict__ Wkva, const float* __restrict__ Wkvb,
    const float* __restrict__ Wout,
    bf16* __restrict__ xb,
    bf16* __restrict__ WfT, bf16* __restrict__ WqbT,
    bf16* __restrict__ WkvbT, bf16* __restrict__ WoutT,
    float2* __restrict__ rope_tab)
{
    int t = blockIdx.x;
    if (t < 8192) {
        size_t i = ((size_t)t * 256 + threadIdx.x) * 4;
        float4 v = *(const float4*)(x + i);
        xb[i]     = (bf16)v.x;
        xb[i + 1] = (bf16)v.y;
        xb[i + 2] = (bf16)v.z;
        xb[i + 3] = (bf16)v.w;
        return;
    }
    t -= 8192;
    if (t >= 9856) {                       // rope table: 256 blocks
        int gid = (t - 9856) * 256 + threadIdx.x;   // 0..65535
        int n = gid >> 5, i = gid & 31;
        float theta = powf(10000.f, -(float)i / 32.f);
        float sn, cs;
        sincosf((float)n * theta, &sn, &cs);
        rope_tab[gid] = make_float2(cs, sn);
        return;
    }
    __shared__ float tile[32][33];
    const float* in; bf16* out; int R, C;
    if (t < 1024)      {            in = Wqa;  out = WfT;                      R = 2048; C = 512;  }
    else if (t < 2176) { t -= 1024; in = Wkva; out = WfT + (size_t)512 * 2048; R = 2048; C = 576;  }
    else if (t < 3712) { t -= 2176; in = Wqb;  out = WqbT;                     R = 512;  C = 3072; }
    else if (t < 5760) { t -= 3712; in = Wkvb; out = WkvbT;                    R = 512;  C = 4096; }
    else               { t -= 5760; in = Wout; out = WoutT;                    R = 2048; C = 2048; }
    int tilesX = (C + 31) >> 5;
    int bx = (t % tilesX) * 32, by = (t / tilesX) * 32;
    int tx = threadIdx.x & 31, ty = threadIdx.x >> 5;
    for (int i = 0; i < 32; i += 8) {
        int r = by + ty + i, c = bx + tx;
        tile[ty + i][tx] = (r < R && c < C) ? in[(size_t)r * C + c] : 0.f;
    }
    __syncthreads();
    for (int i = 0; i < 32; i += 8) {
        int c = bx + ty + i, r = by + tx;
        if (c < C && r < R) out[(size_t)c * R + r] = (bf16)tile[tx][ty + i];
    }
}

// ===========================================================================
// GEMM core body (m97 recipe), 128x128
// ===========================================================================
#define GEMM_BODY(Aptr, LDA, Bptr, LDB, KK, BNIDX)                              \
    __shared__ bf16 As[128 * 32];                                               \
    __shared__ bf16 Bs[128 * 32];                                               \
    const int tid  = threadIdx.x;                                               \
    const int wave = tid >> 6, lane = tid & 63;                                 \
    const int quad = lane >> 4, l16 = lane & 15;                                \
    const int bm = blockIdx.x * 128, bn = (BNIDX) * 128;                        \
    const int wm = (wave >> 1) * 64, wn = (wave & 1) * 64;                      \
    const int srow = lane >> 2, scol = (lane & 3) * 8;                          \
    f32x4 acc[4][4];                                                            \
    for (int i = 0; i < 4; i++)                                                 \
        for (int j = 0; j < 4; j++)                                             \
            acc[i][j] = (f32x4){0.f, 0.f, 0.f, 0.f};                            \
    for (int k0 = 0; k0 < (KK); k0 += 32) {                                     \
        _Pragma("unroll")                                                       \
        for (int s2 = 0; s2 < 2; s2++) {                                        \
            const int seg = wave * 2 + s2;                                      \
            const bf16* ga = (Aptr) + (size_t)(bm + seg * 16 + srow) * (LDA) + k0 + scol; \
            const bf16* gb = (Bptr) + (size_t)(bn + seg * 16 + srow) * (LDB) + k0 + scol; \
            __builtin_amdgcn_global_load_lds(                                   \
                (const __attribute__((address_space(1))) void*)ga,              \
                (__attribute__((address_space(3))) void*)&As[seg * 512], 16, 0, 0); \
            __builtin_amdgcn_global_load_lds(                                   \
                (const __attribute__((address_space(1))) void*)gb,              \
                (__attribute__((address_space(3))) void*)&Bs[seg * 512], 16, 0, 0); \
        }                                                                       \
        __syncthreads();                                                        \
        bf16x8 af[4], bfv[4];                                                   \
        for (int mi = 0; mi < 4; mi++)                                          \
            af[mi] = *(const bf16x8*)&As[(wm + mi * 16 + l16) * 32 + quad * 8]; \
        for (int ni = 0; ni < 4; ni++)                                          \
            bfv[ni] = *(const bf16x8*)&Bs[(wn + ni * 16 + l16) * 32 + quad * 8];\
        for (int mi = 0; mi < 4; mi++)                                          \
            for (int ni = 0; ni < 4; ni++)                                      \
                acc[mi][ni] = __builtin_amdgcn_mfma_f32_16x16x32_bf16(          \
                    af[mi], bfv[ni], acc[mi][ni], 0, 0, 0);                     \
        __syncthreads();                                                        \
    }

// ---------------------------------------------------------------------------
// Generic GEMM with plain epilogue (guards on N)
// ---------------------------------------------------------------------------
template <typename OutT>
__global__ __launch_bounds__(256) void gemm_bf16(
    const bf16* __restrict__ A, int lda,
    const bf16* __restrict__ Bt, int ldb,
    OutT* __restrict__ C, int ldc,
    int N, int K)
{
    GEMM_BODY(A, lda, Bt, ldb, K, blockIdx.y)
    for (int mi = 0; mi < 4; mi++)
        for (int ni = 0; ni < 4; ni++) {
            int col = bn + wn + ni * 16 + l16;
            if (col >= N) continue;
            int row0 = bm + wm + mi * 16 + quad * 4;
            for (int r = 0; r < 4; r++)
                C[(size_t)(row0 + r) * ldc + col] = (OutT)acc[mi][ni][r];
        }
}

// ---------------------------------------------------------------------------
// GEMM1+3: tc[:,0:1088] = x @ [Wqa|Wkva], K=2048. BN=64 tiles -> grid (32,17)
// = 544 blocks (128-tile version had 288 = 1.1/CU starvation).
// ---------------------------------------------------------------------------
__global__ __launch_bounds__(256) void gemm13_n64(
    const bf16* __restrict__ A, const bf16* __restrict__ Bt,
    bf16* __restrict__ tc)
{
    __shared__ bf16 As[128 * 32];
    __shared__ bf16 Bs[64 * 32];
    const int tid  = threadIdx.x;
    const int wave = tid >> 6, lane = tid & 63;
    const int quad = lane >> 4, l16 = lane & 15;
    const int bm = blockIdx.x * 128, bn = blockIdx.y * 64;
    const int srow = lane >> 2, scol = (lane & 3) * 8;
    f32x4 acc[2][4];
    for (int i = 0; i < 2; i++)
        for (int j = 0; j < 4; j++) acc[i][j] = (f32x4){0.f, 0.f, 0.f, 0.f};
    for (int k0 = 0; k0 < 2048; k0 += 32) {
#pragma unroll
        for (int s2 = 0; s2 < 2; s2++) {
            const int seg = wave * 2 + s2;
            const bf16* ga = A + (size_t)(bm + seg * 16 + srow) * 2048 + k0 + scol;
            __builtin_amdgcn_global_load_lds(
                (const __attribute__((address_space(1))) void*)ga,
                (__attribute__((address_space(3))) void*)&As[seg * 512], 16, 0, 0);
            if (s2 == 0) {
                const bf16* gb = Bt + (size_t)(bn + wave * 16 + srow) * 2048 + k0 + scol;
                __builtin_amdgcn_global_load_lds(
                    (const __attribute__((address_space(1))) void*)gb,
                    (__attribute__((address_space(3))) void*)&Bs[wave * 512], 16, 0, 0);
            }
        }
        __syncthreads();
        bf16x8 af[2], bfv[4];
        for (int mi = 0; mi < 2; mi++)
            af[mi] = *(const bf16x8*)&As[(wave * 32 + mi * 16 + l16) * 32 + quad * 8];
        for (int ni = 0; ni < 4; ni++)
            bfv[ni] = *(const bf16x8*)&Bs[(ni * 16 + l16) * 32 + quad * 8];
        for (int mi = 0; mi < 2; mi++)
            for (int ni = 0; ni < 4; ni++)
                acc[mi][ni] = __builtin_amdgcn_mfma_f32_16x16x32_bf16(
                    af[mi], bfv[ni], acc[mi][ni], 0, 0, 0);
        __syncthreads();
    }
    for (int mi = 0; mi < 2; mi++)
        for (int ni = 0; ni < 4; ni++) {
            int col = bn + ni * 16 + l16;          // <= 1087, exact
            int row0 = bm + wave * 32 + mi * 16 + quad * 4;
            for (int r = 0; r < 4; r++)
                tc[(size_t)(row0 + r) * 1152 + col] = (bf16)acc[mi][ni][r];
        }
}

// ---------------------------------------------------------------------------
// GEMM2+GEMM4 merged (grid 32 x 56):
//  by<24 : q = t1 @ Wqb -> RoPE (table) + QSCALE2 -> qf
//  by>=24: kv = ckv @ Wkvb. Even 128-col tiles are pure k_nope -> kf;
//          odd tiles are pure V -> transposed via LDS bounce -> vT directly.
// ---------------------------------------------------------------------------
__global__ __launch_bounds__(256) void gemm_qkv(
    const bf16* __restrict__ tc,
    const bf16* __restrict__ WqbT, const bf16* __restrict__ WkvbT,
    const float2* __restrict__ rope_tab,
    bf16* __restrict__ qf, bf16* __restrict__ kf, bf16* __restrict__ vT)
{
    __shared__ bf16 Vs[64][132];     // v-transpose bounce (pad 128->132)
    const int byAll = blockIdx.y;
    const bool isQ = byAll < 24;
    const bf16* A  = isQ ? tc : tc + 512;
    const bf16* Bt = isQ ? WqbT : WkvbT;
    const int bnIdx = isQ ? byAll : byAll - 24;
    GEMM_BODY(A, 1152, Bt, 512, 512, bnIdx)
    if (isQ) {
        const bool odd = l16 & 1;
        for (int mi = 0; mi < 4; mi++)
            for (int ni = 0; ni < 4; ni++) {
                int col0 = bn + wn + ni * 16;
                int h  = col0 / 192;
                int d0 = col0 - h * 192;
                int d  = d0 + l16;
                bool roped = d0 >= 128;
                int i = roped ? ((d - 128) >> 1) : 0;
                for (int r = 0; r < 4; r++) {
                    int row = bm + wm + mi * 16 + quad * 4 + r;
                    int b = row >> 11, n = row & 2047;
                    float v = acc[mi][ni][r], res;
                    if (roped) {
                        float p = __shfl_xor(v, 1);
                        float2 cs = rope_tab[(n << 5) + i];
                        float x1 = odd ? p : v, x2 = odd ? v : p;
                        res = odd ? (x1 * cs.y + x2 * cs.x) : (x1 * cs.x - x2 * cs.y);
                    } else res = v;
                    qf[(((size_t)(b * HEADS + h)) * SEQ + n) * QHEAD + d] =
                        (bf16)(res * QSCALE2);
                }
            }
    } else if (!(bnIdx & 1)) {     // k_nope block -> kf scatter
        const int h = bnIdx >> 1;
        for (int mi = 0; mi < 4; mi++)
            for (int ni = 0; ni < 4; ni++) {
                int d = wn + ni * 16 + l16;        // 0..127
                for (int r = 0; r < 4; r++) {
                    int row = bm + wm + mi * 16 + quad * 4 + r;
                    int b = row >> 11, n = row & 2047;
                    kf[(((size_t)(b * HEADS + h)) * SEQ + n) * QHEAD + d] =
                        (bf16)acc[mi][ni][r];
                }
            }
    } else {                        // V block -> vT via LDS bounce
        const int h = bnIdx >> 1;
        const int bb = bm >> 11, n0 = bm & 2047;
        const size_t vbase = (size_t)(bb * HEADS + h) * 128 * SEQ;
#pragma unroll
        for (int p = 0; p < 2; p++) {
            if ((wave & 1) == p) {  // waves holding dv half p write their acc
                for (int ni = 0; ni < 4; ni++)
                    for (int mi = 0; mi < 4; mi++)
                        for (int r = 0; r < 4; r++)
                            Vs[ni * 16 + l16][wm + mi * 16 + quad * 4 + r] =
                                (bf16)acc[mi][ni][r];
            }
            __syncthreads();
            {   // all 256 threads: coalesced 64B writes along n
                int dv_l = tid >> 2, seg = tid & 3;
                const bf16* src = &Vs[dv_l][seg * 32];
                bf16* dst = vT + vbase + (size_t)(p * 64 + dv_l) * SEQ + n0 + seg * 32;
                uint4 v0 = *(const uint4*)(src);
                uint4 v1 = *(const uint4*)(src + 8);
                uint4 v2 = *(const uint4*)(src + 16);
                uint4 v3 = *(const uint4*)(src + 24);
                *(uint4*)(dst)      = v0;
                *(uint4*)(dst + 8)  = v1;
                *(uint4*)(dst + 16) = v2;
                *(uint4*)(dst + 24) = v3;
            }
            __syncthreads();
        }
    }
}

// ---------------------------------------------------------------------------
// rope_kpe: kf[bh,n,128..191] from tc cols 1024..1087, table-based RoPE,
// broadcast over 16 heads. 1024 blocks.
// ---------------------------------------------------------------------------
__global__ __launch_bounds__(256) void rope_kpe(
    const bf16* __restrict__ tc, const float2* __restrict__ rope_tab,
    bf16* __restrict__ kf)
{
    int gid = blockIdx.x * 256 + threadIdx.x;
    int row = gid >> 6, j = gid & 63;
    int b = row >> 11, n = row & 2047;
    int i = j >> 1;
    float x1 = (float)tc[(size_t)row * 1152 + 1024 + 2 * i];
    float x2 = (float)tc[(size_t)row * 1152 + 1024 + 2 * i + 1];
    float2 cs = rope_tab[(n << 5) + i];
    bf16 rv = (bf16)((j & 1) ? (x1 * cs.y + x2 * cs.x) : (x1 * cs.x - x2 * cs.y));
    for (int h = 0; h < HEADS; h++)
        kf[(((size_t)(b * HEADS + h)) * SEQ + n) * QHEAD + 128 + j] = rv;
}

// ---------------------------------------------------------------------------
// Flash attention, causal, fixed-shift softmax (round 8, unchanged).
// ---------------------------------------------------------------------------
__global__ __launch_bounds__(256) void attn_fa(
    const bf16* __restrict__ qf, const bf16* __restrict__ kf,
    const bf16* __restrict__ vT, bf16* __restrict__ attn_out)
{
    __shared__ bf16 Ks[64][200];
    __shared__ bf16 Vt[128][72];
    __shared__ bf16 Ps[4][16][72];

    const int bid = blockIdx.x;
    const int xcd = bid & 7, j = bid >> 3;
    const int qt = 31 - (j >> 2);
    const int bh = xcd + 8 * (j & 3);
    const int b = bh >> 4, h = bh & 15;
    const int tid  = threadIdx.x;
    const int wave = tid >> 6, lane = tid & 63;
    const int quad = lane >> 4, l16 = lane & 15;

    bf16x8 aq[6];
    {
        const bf16* qbase = qf + ((size_t)bh * SEQ + qt * 64 + wave * 16 + l16) * QHEAD;
        for (int ks = 0; ks < 6; ks++)
            aq[ks] = *(const bf16x8*)(qbase + ks * 32 + quad * 8);
    }
    f32x4 o[8];
    for (int i = 0; i < 8; i++) o[i] = (f32x4){0.f, 0.f, 0.f, 0.f};
    float lp[4] = {0.f, 0.f, 0.f, 0.f};

    for (int kt = 0; kt <= qt; kt++) {
#pragma unroll
        for (int i = 0; i < 6; i++) {
            int c = tid + i * 256;
            int r = c / 24, col = (c - r * 24) * 8;
            *(uint4*)&Ks[r][col] =
                *(const uint4*)(kf + ((size_t)bh * SEQ + kt * 64 + r) * QHEAD + col);
        }
#pragma unroll
        for (int i = 0; i < 4; i++) {
            int c = tid + i * 256;
            int dv = c >> 3, g = c & 7;
            *(uint4*)&Vt[dv][g * 8] =
                *(const uint4*)(vT + ((size_t)bh * 128 + dv) * SEQ + kt * 64 + g * 8);
        }
        __syncthreads();

        f32x4 sacc[4];
        for (int nt = 0; nt < 4; nt++) sacc[nt] = (f32x4){0.f, 0.f, 0.f, 0.f};
        for (int ks = 0; ks < 6; ks++)
            for (int nt = 0; nt < 4; nt++) {
                bf16x8 bk = *(const bf16x8*)&Ks[nt * 16 + l16][ks * 32 + quad * 8];
                sacc[nt] = __builtin_amdgcn_mfma_f32_16x16x32_bf16(aq[ks], bk, sacc[nt], 0, 0, 0);
            }

        const bool diag = (kt == qt);
#pragma unroll
        for (int r = 0; r < 4; r++) {
            const int qrow = wave * 16 + quad * 4 + r;
#pragma unroll
            for (int nt = 0; nt < 4; nt++) {
                float p;
                if (diag && (nt * 16 + l16 > qrow)) p = 0.f;
                else p = __builtin_amdgcn_exp2f(sacc[nt][r] - CSHIFT);
                lp[r] += p;
                Ps[wave][quad * 4 + r][nt * 16 + l16] = (bf16)p;
            }
        }
        __builtin_amdgcn_sched_barrier(0);

        for (int ks2 = 0; ks2 < 2; ks2++) {
            bf16x8 ap = *(const bf16x8*)&Ps[wave][l16][ks2 * 32 + quad * 8];
            for (int nv = 0; nv < 8; nv++) {
                bf16x8 bv = *(const bf16x8*)&Vt[nv * 16 + l16][ks2 * 32 + quad * 8];
                o[nv] = __builtin_amdgcn_mfma_f32_16x16x32_bf16(ap, bv, o[nv], 0, 0, 0);
            }
        }
        __syncthreads();
    }

#pragma unroll
    for (int r = 0; r < 4; r++) {
        lp[r] += __shfl_xor(lp[r], 8);
        lp[r] += __shfl_xor(lp[r], 4);
        lp[r] += __shfl_xor(lp[r], 2);
        lp[r] += __shfl_xor(lp[r], 1);
    }
    for (int r = 0; r < 4; r++) {
        float inv = 1.f / lp[r];
        size_t row = (size_t)b * SEQ + qt * 64 + wave * 16 + quad * 4 + r;
        for (int nv = 0; nv < 8; nv++)
            attn_out[row * 2048 + h * 128 + nv * 16 + l16] = (bf16)(o[nv][r] * inv);
    }
}

// ---------------------------------------------------------------------------
extern "C" void kernel_launch(void* const* d_in, const int* in_sizes, int n_in,
                              void* d_out, int out_size, void* d_ws, size_t ws_size,
                              hipStream_t stream)
{
    const float* x    = (const float*)d_in[0];
    const float* Wqa  = (const float*)d_in[1];
    const float* Wqb  = (const float*)d_in[2];
    const float* Wkva = (const float*)d_in[3];
    const float* Wkvb = (const float*)d_in[4];
    const float* Wout = (const float*)d_in[5];
    float* out = (float*)d_out;

    char* ws = (char*)d_ws;
    size_t off = 0;
    auto alloc = [&](size_t elems) { char* p = ws + off; off += elems * sizeof(bf16); return (bf16*)p; };
    bf16* xb    = alloc((size_t)ROWS * 2048);   // reused as `attn` later
    bf16* WfT   = alloc((size_t)1152 * 2048);
    bf16* WqbT  = alloc((size_t)3072 * 512);
    bf16* WkvbT = alloc((size_t)4096 * 512);
    bf16* WoutT = alloc((size_t)2048 * 2048);
    bf16* tc    = alloc((size_t)ROWS * 1152);   // [t1(512) | ckv(512) | k_pe(64) | pad]
    bf16* vT    = alloc((size_t)32 * 128 * SEQ);
    bf16* qf    = alloc((size_t)32 * SEQ * QHEAD);
    bf16* kf    = alloc((size_t)32 * SEQ * QHEAD);
    float2* rope_tab = (float2*)alloc((size_t)SEQ * 32 * 4);   // 512KB, 8B-aligned
    bf16* attn  = xb;
    if (off > ws_size) return;

    dim3 blk(256);

    // convert + transposes + rope table, one launch
    prep<<<dim3(18304), blk, 0, stream>>>(x, Wqa, Wqb, Wkva, Wkvb, Wout,
                                          xb, WfT, WqbT, WkvbT, WoutT, rope_tab);

    // GEMM1+3: tc = x @ [Wqa|Wkva], K=2048, BN=64 -> 544 blocks
    gemm13_n64<<<dim3(32, 17), blk, 0, stream>>>(xb, WfT, tc);

    // GEMM2 (RoPE->qf) + GEMM4 (k_nope->kf, V->vT direct), one launch
    gemm_qkv<<<dim3(32, 56), blk, 0, stream>>>(tc, WqbT, WkvbT, rope_tab, qf, kf, vT);

    // k_pe RoPE broadcast (table-based)
    rope_kpe<<<dim3(1024), blk, 0, stream>>>(tc, rope_tab, kf);

    // flash attention
    attn_fa<<<dim3(1024), blk, 0, stream>>>(qf, kf, vT, attn);

    // GEMM5: out = attn @ Wout, K=2048 (fp32 output)
    gemm_bf16<float><<<dim3(32, 16), blk, 0, stream>>>(attn, 2048, WoutT, 2048, out, 2048, 2048, 2048);
}

// Round 10
// 470.705 us; speedup vs baseline: 1.2533x; 1.2533x over previous
//
#include <hip/hip_runtime.h>
#include <math.h>

typedef __bf16 bf16;
typedef __bf16 bf16x8 __attribute__((ext_vector_type(8)));
typedef float f32x4 __attribute__((ext_vector_type(4)));

#define HEADS 16
#define QHEAD 192
#define NB 2
#define SEQ 2048
#define ROWS (NB * SEQ)
/* q pre-scale = log2(e)/sqrt(192): scores arrive in exp2 domain */
#define QSCALE2 0.10411754584f
/* fixed softmax shift: p = 2^(sacc - CSHIFT) = exp(s_nat - 8) */
#define CSHIFT 11.5415603272f

// ---------------------------------------------------------------------------
// prep: x convert (0..8191) + weight transposes (8192..18047) +
// RoPE sin/cos table (18048..18303): tab[n*32+i] = {cos,sin}(n*10000^(-i/32))
// ---------------------------------------------------------------------------
__global__ __launch_bounds__(256) void prep(
    const float* __restrict__ x,
    const float* __restrict__ Wqa, const float* __restrict__ Wqb,
    const float* __restrict__ Wkva, const float* __restrict__ Wkvb,
    const float* __restrict__ Wout,
    bf16* __restrict__ xb,
    bf16* __restrict__ WfT, bf16* __restrict__ WqbT,
    bf16* __restrict__ WkvbT, bf16* __restrict__ WoutT,
    float2* __restrict__ rope_tab)
{
    int t = blockIdx.x;
    if (t < 8192) {
        size_t i = ((size_t)t * 256 + threadIdx.x) * 4;
        float4 v = *(const float4*)(x + i);
        xb[i]     = (bf16)v.x;
        xb[i + 1] = (bf16)v.y;
        xb[i + 2] = (bf16)v.z;
        xb[i + 3] = (bf16)v.w;
        return;
    }
    t -= 8192;
    if (t >= 9856) {                       // rope table: 256 blocks
        int gid = (t - 9856) * 256 + threadIdx.x;   // 0..65535
        int n = gid >> 5, i = gid & 31;
        float theta = powf(10000.f, -(float)i / 32.f);
        float sn, cs;
        sincosf((float)n * theta, &sn, &cs);
        rope_tab[gid] = make_float2(cs, sn);
        return;
    }
    __shared__ float tile[32][33];
    const float* in; bf16* out; int R, C;
    if (t < 1024)      {            in = Wqa;  out = WfT;                      R = 2048; C = 512;  }
    else if (t < 2176) { t -= 1024; in = Wkva; out = WfT + (size_t)512 * 2048; R = 2048; C = 576;  }
    else if (t < 3712) { t -= 2176; in = Wqb;  out = WqbT;                     R = 512;  C = 3072; }
    else if (t < 5760) { t -= 3712; in = Wkvb; out = WkvbT;                    R = 512;  C = 4096; }
    else               { t -= 5760; in = Wout; out = WoutT;                    R = 2048; C = 2048; }
    int tilesX = (C + 31) >> 5;
    int bx = (t % tilesX) * 32, by = (t / tilesX) * 32;
    int tx = threadIdx.x & 31, ty = threadIdx.x >> 5;
    for (int i = 0; i < 32; i += 8) {
        int r = by + ty + i, c = bx + tx;
        tile[ty + i][tx] = (r < R && c < C) ? in[(size_t)r * C + c] : 0.f;
    }
    __syncthreads();
    for (int i = 0; i < 32; i += 8) {
        int c = bx + ty + i, r = by + tx;
        if (c < C && r < R) out[(size_t)c * R + r] = (bf16)tile[tx][ty + i];
    }
}

// ===========================================================================
// GEMM core body (m97 recipe), 128x128
// ===========================================================================
#define GEMM_BODY(Aptr, LDA, Bptr, LDB, KK, BNIDX)                              \
    __shared__ bf16 As[128 * 32];                                               \
    __shared__ bf16 Bs[128 * 32];                                               \
    const int tid  = threadIdx.x;                                               \
    const int wave = tid >> 6, lane = tid & 63;                                 \
    const int quad = lane >> 4, l16 = lane & 15;                                \
    const int bm = blockIdx.x * 128, bn = (BNIDX) * 128;                        \
    const int wm = (wave >> 1) * 64, wn = (wave & 1) * 64;                      \
    const int srow = lane >> 2, scol = (lane & 3) * 8;                          \
    f32x4 acc[4][4];                                                            \
    for (int i = 0; i < 4; i++)                                                 \
        for (int j = 0; j < 4; j++)                                             \
            acc[i][j] = (f32x4){0.f, 0.f, 0.f, 0.f};                            \
    for (int k0 = 0; k0 < (KK); k0 += 32) {                                     \
        _Pragma("unroll")                                                       \
        for (int s2 = 0; s2 < 2; s2++) {                                        \
            const int seg = wave * 2 + s2;                                      \
            const bf16* ga = (Aptr) + (size_t)(bm + seg * 16 + srow) * (LDA) + k0 + scol; \
            const bf16* gb = (Bptr) + (size_t)(bn + seg * 16 + srow) * (LDB) + k0 + scol; \
            __builtin_amdgcn_global_load_lds(                                   \
                (const __attribute__((address_space(1))) void*)ga,              \
                (__attribute__((address_space(3))) void*)&As[seg * 512], 16, 0, 0); \
            __builtin_amdgcn_global_load_lds(                                   \
                (const __attribute__((address_space(1))) void*)gb,              \
                (__attribute__((address_space(3))) void*)&Bs[seg * 512], 16, 0, 0); \
        }                                                                       \
        __syncthreads();                                                        \
        bf16x8 af[4], bfv[4];                                                   \
        for (int mi = 0; mi < 4; mi++)                                          \
            af[mi] = *(const bf16x8*)&As[(wm + mi * 16 + l16) * 32 + quad * 8]; \
        for (int ni = 0; ni < 4; ni++)                                          \
            bfv[ni] = *(const bf16x8*)&Bs[(wn + ni * 16 + l16) * 32 + quad * 8];\
        for (int mi = 0; mi < 4; mi++)                                          \
            for (int ni = 0; ni < 4; ni++)                                      \
                acc[mi][ni] = __builtin_amdgcn_mfma_f32_16x16x32_bf16(          \
                    af[mi], bfv[ni], acc[mi][ni], 0, 0, 0);                     \
        __syncthreads();                                                        \
    }

// ---------------------------------------------------------------------------
// Generic GEMM with plain epilogue (guards on N)
// ---------------------------------------------------------------------------
template <typename OutT>
__global__ __launch_bounds__(256) void gemm_bf16(
    const bf16* __restrict__ A, int lda,
    const bf16* __restrict__ Bt, int ldb,
    OutT* __restrict__ C, int ldc,
    int N, int K)
{
    GEMM_BODY(A, lda, Bt, ldb, K, blockIdx.y)
    for (int mi = 0; mi < 4; mi++)
        for (int ni = 0; ni < 4; ni++) {
            int col = bn + wn + ni * 16 + l16;
            if (col >= N) continue;
            int row0 = bm + wm + mi * 16 + quad * 4;
            for (int r = 0; r < 4; r++)
                C[(size_t)(row0 + r) * ldc + col] = (OutT)acc[mi][ni][r];
        }
}

// ---------------------------------------------------------------------------
// GEMM1+3: tc[:,0:1088] = x @ [Wqa|Wkva], K=2048. BN=64 -> grid (32,17).
// ---------------------------------------------------------------------------
__global__ __launch_bounds__(256) void gemm13_n64(
    const bf16* __restrict__ A, const bf16* __restrict__ Bt,
    bf16* __restrict__ tc)
{
    __shared__ bf16 As[128 * 32];
    __shared__ bf16 Bs[64 * 32];
    const int tid  = threadIdx.x;
    const int wave = tid >> 6, lane = tid & 63;
    const int quad = lane >> 4, l16 = lane & 15;
    const int bm = blockIdx.x * 128, bn = blockIdx.y * 64;
    const int srow = lane >> 2, scol = (lane & 3) * 8;
    f32x4 acc[2][4];
    for (int i = 0; i < 2; i++)
        for (int j = 0; j < 4; j++) acc[i][j] = (f32x4){0.f, 0.f, 0.f, 0.f};
    for (int k0 = 0; k0 < 2048; k0 += 32) {
#pragma unroll
        for (int s2 = 0; s2 < 2; s2++) {
            const int seg = wave * 2 + s2;
            const bf16* ga = A + (size_t)(bm + seg * 16 + srow) * 2048 + k0 + scol;
            __builtin_amdgcn_global_load_lds(
                (const __attribute__((address_space(1))) void*)ga,
                (__attribute__((address_space(3))) void*)&As[seg * 512], 16, 0, 0);
            if (s2 == 0) {
                const bf16* gb = Bt + (size_t)(bn + wave * 16 + srow) * 2048 + k0 + scol;
                __builtin_amdgcn_global_load_lds(
                    (const __attribute__((address_space(1))) void*)gb,
                    (__attribute__((address_space(3))) void*)&Bs[wave * 512], 16, 0, 0);
            }
        }
        __syncthreads();
        bf16x8 af[2], bfv[4];
        for (int mi = 0; mi < 2; mi++)
            af[mi] = *(const bf16x8*)&As[(wave * 32 + mi * 16 + l16) * 32 + quad * 8];
        for (int ni = 0; ni < 4; ni++)
            bfv[ni] = *(const bf16x8*)&Bs[(ni * 16 + l16) * 32 + quad * 8];
        for (int mi = 0; mi < 2; mi++)
            for (int ni = 0; ni < 4; ni++)
                acc[mi][ni] = __builtin_amdgcn_mfma_f32_16x16x32_bf16(
                    af[mi], bfv[ni], acc[mi][ni], 0, 0, 0);
        __syncthreads();
    }
    for (int mi = 0; mi < 2; mi++)
        for (int ni = 0; ni < 4; ni++) {
            int col = bn + ni * 16 + l16;
            int row0 = bm + wave * 32 + mi * 16 + quad * 4;
            for (int r = 0; r < 4; r++)
                tc[(size_t)(row0 + r) * 1152 + col] = (bf16)acc[mi][ni][r];
        }
}

// ---------------------------------------------------------------------------
// GEMM2 standalone: q = t1 @ Wqb -> table RoPE + QSCALE2 -> qf. Grid (32,24).
// (Split from the merged qkv kernel: 3-branch epilogue spilled acc — r9.)
// ---------------------------------------------------------------------------
__global__ __launch_bounds__(256) void gemm_qf(
    const bf16* __restrict__ tc, const bf16* __restrict__ WqbT,
    const float2* __restrict__ rope_tab, bf16* __restrict__ qf)
{
    GEMM_BODY(tc, 1152, WqbT, 512, 512, blockIdx.y)
    const bool odd = l16 & 1;
    for (int mi = 0; mi < 4; mi++)
        for (int ni = 0; ni < 4; ni++) {
            int col0 = bn + wn + ni * 16;
            int h  = col0 / 192;
            int d0 = col0 - h * 192;
            int d  = d0 + l16;
            bool roped = d0 >= 128;
            int i = roped ? ((d - 128) >> 1) : 0;
            for (int r = 0; r < 4; r++) {
                int row = bm + wm + mi * 16 + quad * 4 + r;
                int b = row >> 11, n = row & 2047;
                float v = acc[mi][ni][r], res;
                if (roped) {
                    float p = __shfl_xor(v, 1);
                    float2 cs = rope_tab[(n << 5) + i];
                    float x1 = odd ? p : v, x2 = odd ? v : p;
                    res = odd ? (x1 * cs.y + x2 * cs.x) : (x1 * cs.x - x2 * cs.y);
                } else res = v;
                qf[(((size_t)(b * HEADS + h)) * SEQ + n) * QHEAD + d] =
                    (bf16)(res * QSCALE2);
            }
        }
}

// ---------------------------------------------------------------------------
// GEMM4 standalone: kv = ckv @ Wkvb. Grid (32,32). Even 128-col tiles are
// pure k_nope -> kf scatter; odd tiles are pure V -> vT via LDS bounce.
// ---------------------------------------------------------------------------
__global__ __launch_bounds__(256) void gemm_kv(
    const bf16* __restrict__ tc, const bf16* __restrict__ WkvbT,
    bf16* __restrict__ kf, bf16* __restrict__ vT)
{
    __shared__ bf16 Vs[64][132];
    GEMM_BODY(tc + 512, 1152, WkvbT, 512, 512, blockIdx.y)
    const int bnIdx = blockIdx.y;
    const int h = bnIdx >> 1;
    if (!(bnIdx & 1)) {            // k_nope -> kf
        for (int mi = 0; mi < 4; mi++)
            for (int ni = 0; ni < 4; ni++) {
                int d = wn + ni * 16 + l16;
                for (int r = 0; r < 4; r++) {
                    int row = bm + wm + mi * 16 + quad * 4 + r;
                    int b = row >> 11, n = row & 2047;
                    kf[(((size_t)(b * HEADS + h)) * SEQ + n) * QHEAD + d] =
                        (bf16)acc[mi][ni][r];
                }
            }
    } else {                        // V -> vT via LDS bounce
        const int bb = bm >> 11, n0 = bm & 2047;
        const size_t vbase = (size_t)(bb * HEADS + h) * 128 * SEQ;
#pragma unroll
        for (int p = 0; p < 2; p++) {
            if ((wave & 1) == p) {
                for (int ni = 0; ni < 4; ni++)
                    for (int mi = 0; mi < 4; mi++)
                        for (int r = 0; r < 4; r++)
                            Vs[ni * 16 + l16][wm + mi * 16 + quad * 4 + r] =
                                (bf16)acc[mi][ni][r];
            }
            __syncthreads();
            {
                int dv_l = tid >> 2, seg = tid & 3;
                const bf16* src = &Vs[dv_l][seg * 32];
                bf16* dst = vT + vbase + (size_t)(p * 64 + dv_l) * SEQ + n0 + seg * 32;
                uint4 v0 = *(const uint4*)(src);
                uint4 v1 = *(const uint4*)(src + 8);
                uint4 v2 = *(const uint4*)(src + 16);
                uint4 v3 = *(const uint4*)(src + 24);
                *(uint4*)(dst)      = v0;
                *(uint4*)(dst + 8)  = v1;
                *(uint4*)(dst + 16) = v2;
                *(uint4*)(dst + 24) = v3;
            }
            __syncthreads();
        }
    }
}

// ---------------------------------------------------------------------------
// rope_kpe: kf[bh,n,128..191] from tc cols 1024..1087, table-based RoPE,
// broadcast over 16 heads. 1024 blocks.
// ---------------------------------------------------------------------------
__global__ __launch_bounds__(256) void rope_kpe(
    const bf16* __restrict__ tc, const float2* __restrict__ rope_tab,
    bf16* __restrict__ kf)
{
    int gid = blockIdx.x * 256 + threadIdx.x;
    int row = gid >> 6, j = gid & 63;
    int b = row >> 11, n = row & 2047;
    int i = j >> 1;
    float x1 = (float)tc[(size_t)row * 1152 + 1024 + 2 * i];
    float x2 = (float)tc[(size_t)row * 1152 + 1024 + 2 * i + 1];
    float2 cs = rope_tab[(n << 5) + i];
    bf16 rv = (bf16)((j & 1) ? (x1 * cs.y + x2 * cs.x) : (x1 * cs.x - x2 * cs.y));
    for (int h = 0; h < HEADS; h++)
        kf[(((size_t)(b * HEADS + h)) * SEQ + n) * QHEAD + 128 + j] = rv;
}

// ---------------------------------------------------------------------------
// Flash attention, causal, fixed-shift softmax (round 8, unchanged).
// ---------------------------------------------------------------------------
__global__ __launch_bounds__(256) void attn_fa(
    const bf16* __restrict__ qf, const bf16* __restrict__ kf,
    const bf16* __restrict__ vT, bf16* __restrict__ attn_out)
{
    __shared__ bf16 Ks[64][200];
    __shared__ bf16 Vt[128][72];
    __shared__ bf16 Ps[4][16][72];

    const int bid = blockIdx.x;
    const int xcd = bid & 7, j = bid >> 3;
    const int qt = 31 - (j >> 2);
    const int bh = xcd + 8 * (j & 3);
    const int b = bh >> 4, h = bh & 15;
    const int tid  = threadIdx.x;
    const int wave = tid >> 6, lane = tid & 63;
    const int quad = lane >> 4, l16 = lane & 15;

    bf16x8 aq[6];
    {
        const bf16* qbase = qf + ((size_t)bh * SEQ + qt * 64 + wave * 16 + l16) * QHEAD;
        for (int ks = 0; ks < 6; ks++)
            aq[ks] = *(const bf16x8*)(qbase + ks * 32 + quad * 8);
    }
    f32x4 o[8];
    for (int i = 0; i < 8; i++) o[i] = (f32x4){0.f, 0.f, 0.f, 0.f};
    float lp[4] = {0.f, 0.f, 0.f, 0.f};

    for (int kt = 0; kt <= qt; kt++) {
#pragma unroll
        for (int i = 0; i < 6; i++) {
            int c = tid + i * 256;
            int r = c / 24, col = (c - r * 24) * 8;
            *(uint4*)&Ks[r][col] =
                *(const uint4*)(kf + ((size_t)bh * SEQ + kt * 64 + r) * QHEAD + col);
        }
#pragma unroll
        for (int i = 0; i < 4; i++) {
            int c = tid + i * 256;
            int dv = c >> 3, g = c & 7;
            *(uint4*)&Vt[dv][g * 8] =
                *(const uint4*)(vT + ((size_t)bh * 128 + dv) * SEQ + kt * 64 + g * 8);
        }
        __syncthreads();

        f32x4 sacc[4];
        for (int nt = 0; nt < 4; nt++) sacc[nt] = (f32x4){0.f, 0.f, 0.f, 0.f};
        for (int ks = 0; ks < 6; ks++)
            for (int nt = 0; nt < 4; nt++) {
                bf16x8 bk = *(const bf16x8*)&Ks[nt * 16 + l16][ks * 32 + quad * 8];
                sacc[nt] = __builtin_amdgcn_mfma_f32_16x16x32_bf16(aq[ks], bk, sacc[nt], 0, 0, 0);
            }

        const bool diag = (kt == qt);
#pragma unroll
        for (int r = 0; r < 4; r++) {
            const int qrow = wave * 16 + quad * 4 + r;
#pragma unroll
            for (int nt = 0; nt < 4; nt++) {
                float p;
                if (diag && (nt * 16 + l16 > qrow)) p = 0.f;
                else p = __builtin_amdgcn_exp2f(sacc[nt][r] - CSHIFT);
                lp[r] += p;
                Ps[wave][quad * 4 + r][nt * 16 + l16] = (bf16)p;
            }
        }
        __builtin_amdgcn_sched_barrier(0);

        for (int ks2 = 0; ks2 < 2; ks2++) {
            bf16x8 ap = *(const bf16x8*)&Ps[wave][l16][ks2 * 32 + quad * 8];
            for (int nv = 0; nv < 8; nv++) {
                bf16x8 bv = *(const bf16x8*)&Vt[nv * 16 + l16][ks2 * 32 + quad * 8];
                o[nv] = __builtin_amdgcn_mfma_f32_16x16x32_bf16(ap, bv, o[nv], 0, 0, 0);
            }
        }
        __syncthreads();
    }

#pragma unroll
    for (int r = 0; r < 4; r++) {
        lp[r] += __shfl_xor(lp[r], 8);
        lp[r] += __shfl_xor(lp[r], 4);
        lp[r] += __shfl_xor(lp[r], 2);
        lp[r] += __shfl_xor(lp[r], 1);
    }
    for (int r = 0; r < 4; r++) {
        float inv = 1.f / lp[r];
        size_t row = (size_t)b * SEQ + qt * 64 + wave * 16 + quad * 4 + r;
        for (int nv = 0; nv < 8; nv++)
            attn_out[row * 2048 + h * 128 + nv * 16 + l16] = (bf16)(o[nv][r] * inv);
    }
}

// ---------------------------------------------------------------------------
extern "C" void kernel_launch(void* const* d_in, const int* in_sizes, int n_in,
                              void* d_out, int out_size, void* d_ws, size_t ws_size,
                              hipStream_t stream)
{
    const float* x    = (const float*)d_in[0];
    const float* Wqa  = (const float*)d_in[1];
    const float* Wqb  = (const float*)d_in[2];
    const float* Wkva = (const float*)d_in[3];
    const float* Wkvb = (const float*)d_in[4];
    const float* Wout = (const float*)d_in[5];
    float* out = (float*)d_out;

    char* ws = (char*)d_ws;
    size_t off = 0;
    auto alloc = [&](size_t elems) { char* p = ws + off; off += elems * sizeof(bf16); return (bf16*)p; };
    bf16* xb    = alloc((size_t)ROWS * 2048);   // reused as `attn` later
    bf16* WfT   = alloc((size_t)1152 * 2048);
    bf16* WqbT  = alloc((size_t)3072 * 512);
    bf16* WkvbT = alloc((size_t)4096 * 512);
    bf16* WoutT = alloc((size_t)2048 * 2048);
    bf16* tc    = alloc((size_t)ROWS * 1152);   // [t1(512) | ckv(512) | k_pe(64) | pad]
    bf16* vT    = alloc((size_t)32 * 128 * SEQ);
    bf16* qf    = alloc((size_t)32 * SEQ * QHEAD);
    bf16* kf    = alloc((size_t)32 * SEQ * QHEAD);
    float2* rope_tab = (float2*)alloc((size_t)SEQ * 32 * 4);   // 512KB, 8B-aligned
    bf16* attn  = xb;
    if (off > ws_size) return;

    dim3 blk(256);

    // convert + transposes + rope table, one launch
    prep<<<dim3(18304), blk, 0, stream>>>(x, Wqa, Wqb, Wkva, Wkvb, Wout,
                                          xb, WfT, WqbT, WkvbT, WoutT, rope_tab);

    // GEMM1+3: tc = x @ [Wqa|Wkva], K=2048, BN=64 -> 544 blocks
    gemm13_n64<<<dim3(32, 17), blk, 0, stream>>>(xb, WfT, tc);

    // GEMM2: table RoPE -> qf  (separate kernel: merged 3-branch spilled, r9)
    gemm_qf<<<dim3(32, 24), blk, 0, stream>>>(tc, WqbT, rope_tab, qf);
    // GEMM4: k_nope -> kf, V -> vT (LDS bounce)
    gemm_kv<<<dim3(32, 32), blk, 0, stream>>>(tc, WkvbT, kf, vT);

    // k_pe RoPE broadcast (table-based)
    rope_kpe<<<dim3(1024), blk, 0, stream>>>(tc, rope_tab, kf);

    // flash attention
    attn_fa<<<dim3(1024), blk, 0, stream>>>(qf, kf, vT, attn);

    // GEMM5: out = attn @ Wout, K=2048 (fp32 output)
    gemm_bf16<float><<<dim3(32, 16), blk, 0, stream>>>(attn, 2048, WoutT, 2048, out, 2048, 2048, 2048);
}